// Round 1
// 909.163 us; speedup vs baseline: 1.2684x; 1.2684x over previous
//
#include <hip/hip_runtime.h>
#include <hip/hip_bf16.h>
#include <cstdint>

#define H1 8
#define C1 64      // H1*D1
#define D2 128
#define FIN 256
#define NEG 0.2f
#define EPSS 1e-16f
#define CH 1024    // nodes per scan chunk
#define NPW 16     // gemm1: nodes per wave
#define NPB 64     // gemm1: nodes per block (4 waves)

template<typename T> __device__ __forceinline__ float toF(T v);
template<> __device__ __forceinline__ float toF<float>(float v) { return v; }
template<> __device__ __forceinline__ float toF<__hip_bfloat16>(__hip_bfloat16 v) { return __bfloat162float(v); }
template<typename T> __device__ __forceinline__ T fromF(float v);
template<> __device__ __forceinline__ float fromF<float>(float v) { return v; }
template<> __device__ __forceinline__ __hip_bfloat16 fromF<__hip_bfloat16>(float v) { return __float2bfloat16(v); }

__device__ __forceinline__ float bcast_lane(float v, int lane) {
    return __int_as_float(__builtin_amdgcn_readlane(__float_as_int(v), lane));
}

// ---------------- GEMM1: h1 = x @ W1, fused alpha_src1/alpha_dst1 ----------------
// v2: 16 nodes per wave (64/block). 16 independent acc chains -> ILP-bound not
// latency-bound; 64KB LDS fill amortized 16x; readlane (uniform k4) instead of
// shfl keeps the k-loop rolled (no ds_bpermute, no 64KB unrolled body).
template<typename T>
__global__ __launch_bounds__(256) void k_gemm1(const float* __restrict__ x,
    const float* __restrict__ W1, const float* __restrict__ a_src1,
    const float* __restrict__ a_dst1, T* __restrict__ h1,
    float* __restrict__ asrc1, float* __restrict__ adst1, int N)
{
    __shared__ float Ws[FIN * C1];                 // 64 KB
    for (int i = threadIdx.x; i < FIN * C1 / 4; i += 256)
        reinterpret_cast<float4*>(Ws)[i] = reinterpret_cast<const float4*>(W1)[i];

    int wave = threadIdx.x >> 6, lane = threadIdx.x & 63;
    int n0 = blockIdx.x * NPB + wave * NPW;

    float4 xv[NPW];
    #pragma unroll
    for (int i = 0; i < NPW; ++i) {
        int n = n0 + i;
        if (n < N) xv[i] = reinterpret_cast<const float4*>(x + (size_t)n * FIN)[lane];
        else       xv[i] = make_float4(0.f, 0.f, 0.f, 0.f);
    }
    float as_l = a_src1[lane];
    float ad_l = a_dst1[lane];

    __syncthreads();

    float acc[NPW];
    #pragma unroll
    for (int i = 0; i < NPW; ++i) acc[i] = 0.f;

    #pragma unroll 4
    for (int k4 = 0; k4 < 64; ++k4) {
        const float* w = &Ws[(k4 * 4) * C1 + lane];
        float w0 = w[0];
        float w1 = w[C1];
        float w2 = w[2 * C1];
        float w3 = w[3 * C1];
        #pragma unroll
        for (int i = 0; i < NPW; ++i) {
            float x0 = bcast_lane(xv[i].x, k4);
            float x1 = bcast_lane(xv[i].y, k4);
            float x2 = bcast_lane(xv[i].z, k4);
            float x3 = bcast_lane(xv[i].w, k4);
            acc[i] = fmaf(x0, w0, acc[i]);
            acc[i] = fmaf(x1, w1, acc[i]);
            acc[i] = fmaf(x2, w2, acc[i]);
            acc[i] = fmaf(x3, w3, acc[i]);
        }
    }

    #pragma unroll
    for (int i = 0; i < NPW; ++i) {
        int n = n0 + i;
        if (n >= N) continue;
        h1[(size_t)n * C1 + lane] = fromF<T>(acc[i]);
        float vs = acc[i] * as_l;
        float vd = acc[i] * ad_l;
        #pragma unroll
        for (int off = 1; off < 8; off <<= 1) {
            vs += __shfl_xor(vs, off);
            vd += __shfl_xor(vd, off);
        }
        if ((lane & 7) == 0) {
            int h = lane >> 3;
            asrc1[n * H1 + h] = vs;
            adst1[n * H1 + h] = vd;
        }
    }
}

// ---------------- wsrc/wdst = W2 @ a_src2 / W2 @ a_dst2  (64 each) ----------------
__global__ __launch_bounds__(128) void k_wvec(const float* __restrict__ W2,
    const float* __restrict__ a_src2, const float* __restrict__ a_dst2,
    float* __restrict__ wsrc, float* __restrict__ wdst)
{
    int t = threadIdx.x;
    int k = t & 63;
    const float* a = (t < 64) ? a_src2 : a_dst2;
    float s = 0.f;
    for (int c = 0; c < D2; ++c) s = fmaf(W2[k * D2 + c], a[c], s);
    if (t < 64) wsrc[k] = s; else wdst[k] = s;
}

// ---------------- CSR build ----------------
__global__ void k_count(const int* __restrict__ ei, int E, int N,
                        int* __restrict__ deg)
{
    int tot = E + N;
    for (int e = blockIdx.x * blockDim.x + threadIdx.x; e < tot;
         e += gridDim.x * blockDim.x) {
        int dst = (e < E) ? ei[(size_t)E + e] : (e - E);
        atomicAdd(&deg[dst], 1);
    }
}

// scan phase A: per-chunk local exclusive scan (CH=1024 nodes per block, padded)
__global__ __launch_bounds__(256) void k_scanA(const int* __restrict__ deg,
    int* __restrict__ ptr, int* __restrict__ chunkSum)
{
    __shared__ int wtot[4];
    int b = blockIdx.x, t = threadIdx.x;
    int lane = t & 63, wave = t >> 6;
    int4 v = reinterpret_cast<const int4*>(deg + (size_t)b * CH)[t];
    int s = v.x + v.y + v.z + v.w;
    int incl = s;
    #pragma unroll
    for (int off = 1; off < 64; off <<= 1) {
        int tt = __shfl_up(incl, off);
        if (lane >= off) incl += tt;
    }
    if (lane == 63) wtot[wave] = incl;
    __syncthreads();
    int woff = 0;
    #pragma unroll
    for (int w = 0; w < 4; ++w) if (w < wave) woff += wtot[w];
    int excl = woff + incl - s;
    int i0 = b * CH + t * 4;
    ptr[i0 + 0] = excl;
    ptr[i0 + 1] = excl + v.x;
    ptr[i0 + 2] = excl + v.x + v.y;
    ptr[i0 + 3] = excl + v.x + v.y + v.z;
    if (t == 255) chunkSum[b] = woff + incl;
}

// scan phase B: serial scan over chunk sums (NB ~ 98, trivial)
__global__ void k_scanB(const int* __restrict__ chunkSum, int* __restrict__ chunkOff,
                        int NB, int* __restrict__ ptrN)
{
    if (threadIdx.x == 0) {
        int c = 0;
        for (int b = 0; b < NB; ++b) { chunkOff[b] = c; c += chunkSum[b]; }
        *ptrN = c;
    }
}

// scan phase C: add chunk offsets, init cursor
__global__ __launch_bounds__(256) void k_scanC(int* __restrict__ ptr,
    int* __restrict__ cursor, const int* __restrict__ chunkOff, int N)
{
    int b = blockIdx.x;
    int off = chunkOff[b];
    int i0 = b * CH + threadIdx.x * 4;
    #pragma unroll
    for (int k = 0; k < 4; ++k) {
        int i = i0 + k;
        if (i < N) { int v = ptr[i] + off; ptr[i] = v; cursor[i] = v; }
    }
}

__global__ void k_scatter(const int* __restrict__ ei, int E, int N,
                          int* __restrict__ cursor, int* __restrict__ edge_src)
{
    int tot = E + N;
    for (int e = blockIdx.x * blockDim.x + threadIdx.x; e < tot;
         e += gridDim.x * blockDim.x) {
        int src, dst;
        if (e < E) { src = ei[e]; dst = ei[(size_t)E + e]; }
        else       { src = e - E; dst = e - E; }
        int pos = atomicAdd(&cursor[dst], 1);
        edge_src[pos] = src;
    }
}

// -------- Layer-1 aggregation: online softmax, fused bias+ELU + alpha2 prep --------
template<typename T>
__global__ __launch_bounds__(256) void k_agg1(const int* __restrict__ ptr,
    const int* __restrict__ edge_src, const T* __restrict__ h1,
    const float* __restrict__ asrc1, const float* __restrict__ adst1,
    const float* __restrict__ b1, const float* __restrict__ wsrc,
    const float* __restrict__ wdst, T* __restrict__ hmid,
    float* __restrict__ asrc2, float* __restrict__ adst2, int N)
{
    int wave = threadIdx.x >> 6, lane = threadIdx.x & 63;
    int n = blockIdx.x * 4 + wave;
    if (n >= N) return;
    int h = lane >> 3;
    int start = ptr[n], end = ptr[n + 1];
    float adst = adst1[n * H1 + h];
    float m = -1e30f, sum = 0.f, acc = 0.f;
    for (int e = start; e < end; ++e) {
        int s = edge_src[e];
        float ev = asrc1[s * H1 + h] + adst;
        ev = ev > 0.f ? ev : NEG * ev;
        float hv = toF(h1[(size_t)s * C1 + lane]);
        float mn = fmaxf(m, ev);
        float sc = __expf(m - mn);
        float p  = __expf(ev - mn);
        sum = fmaf(sum, sc, p);
        acc = fmaf(acc, sc, p * hv);
        m = mn;
    }
    float o = acc / (sum + EPSS) + b1[lane];
    o = o > 0.f ? o : (expf(o) - 1.f);   // ELU
    hmid[(size_t)n * C1 + lane] = fromF<T>(o);
    float vs = o * wsrc[lane];
    float vd = o * wdst[lane];
    #pragma unroll
    for (int off = 1; off < 64; off <<= 1) {
        vs += __shfl_xor(vs, off);
        vd += __shfl_xor(vd, off);
    }
    if (lane == 0) { asrc2[n] = vs; adst2[n] = vd; }
}

// ------ Layer-2: online-softmax aggregation in hmid-space + fused W2 GEMM + bias ------
template<typename T>
__global__ __launch_bounds__(256) void k_agg2out(const int* __restrict__ ptr,
    const int* __restrict__ edge_src, const T* __restrict__ hmid,
    const float* __restrict__ asrc2, const float* __restrict__ adst2,
    const float* __restrict__ W2, const float* __restrict__ b2,
    float* __restrict__ out, int N)
{
    __shared__ float Ws[C1 * D2];                  // 32 KB
    for (int i = threadIdx.x; i < C1 * D2; i += 256) Ws[i] = W2[i];
    __syncthreads();
    int wave = threadIdx.x >> 6, lane = threadIdx.x & 63;
    int n = blockIdx.x * 4 + wave;
    if (n >= N) return;
    int start = ptr[n], end = ptr[n + 1];
    float adst = adst2[n];
    float m = -1e30f, sum = 0.f, acc = 0.f;
    for (int e = start; e < end; ++e) {
        int s = edge_src[e];
        float ev = asrc2[s] + adst;
        ev = ev > 0.f ? ev : NEG * ev;
        float hv = toF(hmid[(size_t)s * C1 + lane]);
        float mn = fmaxf(m, ev);
        float sc = __expf(m - mn);
        float p  = __expf(ev - mn);
        sum = fmaf(sum, sc, p);
        acc = fmaf(acc, sc, p * hv);
        m = mn;
    }
    float aggv = acc / (sum + EPSS);
    float acc0 = 0.f, acc1 = 0.f;
    #pragma unroll
    for (int k = 0; k < 64; ++k) {
        float xk = __shfl(aggv, k);
        acc0 = fmaf(xk, Ws[k * D2 + lane], acc0);
        acc1 = fmaf(xk, Ws[k * D2 + 64 + lane], acc1);
    }
    out[(size_t)n * D2 + lane]      = acc0 + b2[lane];
    out[(size_t)n * D2 + 64 + lane] = acc1 + b2[64 + lane];
}

extern "C" void kernel_launch(void* const* d_in, const int* in_sizes, int n_in,
                              void* d_out, int out_size, void* d_ws, size_t ws_size,
                              hipStream_t stream)
{
    const float* x      = (const float*)d_in[0];
    const int*   ei     = (const int*)d_in[1];
    const float* W1     = (const float*)d_in[2];
    const float* a_src1 = (const float*)d_in[3];
    const float* a_dst1 = (const float*)d_in[4];
    const float* b1     = (const float*)d_in[5];
    const float* W2     = (const float*)d_in[6];
    const float* a_src2 = (const float*)d_in[7];
    const float* a_dst2 = (const float*)d_in[8];
    const float* b2     = (const float*)d_in[9];
    float* out = (float*)d_out;

    const int N = in_sizes[0] / FIN;
    const int E = in_sizes[1] / 2;
    const int Etot = E + N;
    const int NB = (N + CH - 1) / CH;     // scan chunks
    const size_t NP = (size_t)NB * CH;    // padded node count

    // workspace requirement: common part + 2 * N*C1 * elemsize
    const size_t common =
        ((size_t)N * H1 * 4 + 255 & ~(size_t)255) * 2 +   // asrc1, adst1
        (((size_t)N * 4 + 255) & ~(size_t)255) * 2 +       // asrc2, adst2
        512 +                                              // wsrc, wdst
        (((size_t)NP * 4 + 255) & ~(size_t)255) * 2 +      // deg, cursor
        (((size_t)(NP + 1) * 4 + 255) & ~(size_t)255) +    // ptr
        (((size_t)NB * 4 + 255) & ~(size_t)255) * 2 +      // chunkSum, chunkOff
        (((size_t)Etot * 4 + 255) & ~(size_t)255) +        // edge_src
        4096;                                              // slack
    const bool f32path = ws_size >= common + 2 * ((size_t)N * C1 * 4 + 256);

    char* ws = (char*)d_ws;
    size_t off = 0;
    auto alloc = [&](size_t bytes) -> void* {
        void* p = ws + off;
        off = (off + bytes + 255) & ~(size_t)255;
        return p;
    };
    const size_t es = f32path ? 4 : 2;
    void*  h1v    = alloc((size_t)N * C1 * es);
    void*  hmidv  = alloc((size_t)N * C1 * es);
    float* asrc1  = (float*)alloc((size_t)N * H1 * 4);
    float* adst1  = (float*)alloc((size_t)N * H1 * 4);
    float* asrc2  = (float*)alloc((size_t)N * 4);
    float* adst2  = (float*)alloc((size_t)N * 4);
    float* wsrc   = (float*)alloc(64 * 4);
    float* wdst   = (float*)alloc(64 * 4);
    int*   deg    = (int*)alloc(NP * 4);
    int*   ptr    = (int*)alloc((NP + 1) * 4);
    int*   cursor = (int*)alloc(NP * 4);
    int*   chunkSum = (int*)alloc((size_t)NB * 4);
    int*   chunkOff = (int*)alloc((size_t)NB * 4);
    int*   edge_src = (int*)alloc((size_t)Etot * 4);

    const int nodeBlocks = (N + 3) / 4;
    const int g1Blocks = (N + NPB - 1) / NPB;

    // CSR build (dst-indexed)
    hipMemsetAsync(deg, 0, NP * 4, stream);
    k_count<<<2048, 256, 0, stream>>>(ei, E, N, deg);
    k_scanA<<<NB, 256, 0, stream>>>(deg, ptr, chunkSum);
    k_scanB<<<1, 64, 0, stream>>>(chunkSum, chunkOff, NB, ptr + N);
    k_scanC<<<NB, 256, 0, stream>>>(ptr, cursor, chunkOff, N);
    k_scatter<<<2048, 256, 0, stream>>>(ei, E, N, cursor, edge_src);

    k_wvec<<<1, 128, 0, stream>>>(W2, a_src2, a_dst2, wsrc, wdst);

    if (f32path) {
        float* h1 = (float*)h1v; float* hmid = (float*)hmidv;
        k_gemm1<float><<<g1Blocks, 256, 0, stream>>>(x, W1, a_src1, a_dst1, h1, asrc1, adst1, N);
        k_agg1<float><<<nodeBlocks, 256, 0, stream>>>(ptr, edge_src, h1, asrc1, adst1, b1,
                                                      wsrc, wdst, hmid, asrc2, adst2, N);
        k_agg2out<float><<<nodeBlocks, 256, 0, stream>>>(ptr, edge_src, hmid, asrc2, adst2,
                                                         W2, b2, out, N);
    } else {
        __hip_bfloat16* h1 = (__hip_bfloat16*)h1v; __hip_bfloat16* hmid = (__hip_bfloat16*)hmidv;
        k_gemm1<__hip_bfloat16><<<g1Blocks, 256, 0, stream>>>(x, W1, a_src1, a_dst1, h1, asrc1, adst1, N);
        k_agg1<__hip_bfloat16><<<nodeBlocks, 256, 0, stream>>>(ptr, edge_src, h1, asrc1, adst1, b1,
                                                               wsrc, wdst, hmid, asrc2, adst2, N);
        k_agg2out<__hip_bfloat16><<<nodeBlocks, 256, 0, stream>>>(ptr, edge_src, hmid, asrc2, adst2,
                                                                  W2, b2, out, N);
    }
}

// Round 2
// 652.154 us; speedup vs baseline: 1.7682x; 1.3941x over previous
//
#include <hip/hip_runtime.h>
#include <hip/hip_bf16.h>
#include <cstdint>

#define H1 8
#define C1 64      // H1*D1
#define D2 128
#define FIN 256
#define NEG 0.2f
#define EPSS 1e-16f
#define CH 1024    // nodes per scan chunk
#define NPW 16     // gemm1: nodes per wave
#define NPB 64     // gemm1: nodes per block (4 waves)

template<typename T> __device__ __forceinline__ float toF(T v);
template<> __device__ __forceinline__ float toF<float>(float v) { return v; }
template<> __device__ __forceinline__ float toF<__hip_bfloat16>(__hip_bfloat16 v) { return __bfloat162float(v); }
template<typename T> __device__ __forceinline__ T fromF(float v);
template<> __device__ __forceinline__ float fromF<float>(float v) { return v; }
template<> __device__ __forceinline__ __hip_bfloat16 fromF<__hip_bfloat16>(float v) { return __float2bfloat16(v); }

__device__ __forceinline__ float bcast_lane(float v, int lane) {
    return __int_as_float(__builtin_amdgcn_readlane(__float_as_int(v), lane));
}

// online-softmax chain update (one edge into one chain)
__device__ __forceinline__ void chain_upd(float ev, float hv,
                                          float& m, float& s, float& a)
{
    float mn = fmaxf(m, ev);
    float sc = __expf(m - mn);
    float p  = __expf(ev - mn);
    s = fmaf(s, sc, p);
    a = fmaf(a, sc, p * hv);
    m = mn;
}

// ---------------- GEMM1: h1 = x @ W1, fused alpha_src1/alpha_dst1 ----------------
// 16 nodes per wave (64/block): 16 independent acc chains -> ILP-bound, LDS fill
// amortized 16x; readlane (uniform k4) keeps the k-loop rolled.
template<typename T>
__global__ __launch_bounds__(256) void k_gemm1(const float* __restrict__ x,
    const float* __restrict__ W1, const float* __restrict__ a_src1,
    const float* __restrict__ a_dst1, T* __restrict__ h1,
    float* __restrict__ asrc1, float* __restrict__ adst1, int N)
{
    __shared__ float Ws[FIN * C1];                 // 64 KB
    for (int i = threadIdx.x; i < FIN * C1 / 4; i += 256)
        reinterpret_cast<float4*>(Ws)[i] = reinterpret_cast<const float4*>(W1)[i];

    int wave = threadIdx.x >> 6, lane = threadIdx.x & 63;
    int n0 = blockIdx.x * NPB + wave * NPW;

    float4 xv[NPW];
    #pragma unroll
    for (int i = 0; i < NPW; ++i) {
        int n = n0 + i;
        if (n < N) xv[i] = reinterpret_cast<const float4*>(x + (size_t)n * FIN)[lane];
        else       xv[i] = make_float4(0.f, 0.f, 0.f, 0.f);
    }
    float as_l = a_src1[lane];
    float ad_l = a_dst1[lane];

    __syncthreads();

    float acc[NPW];
    #pragma unroll
    for (int i = 0; i < NPW; ++i) acc[i] = 0.f;

    #pragma unroll 4
    for (int k4 = 0; k4 < 64; ++k4) {
        const float* w = &Ws[(k4 * 4) * C1 + lane];
        float w0 = w[0];
        float w1 = w[C1];
        float w2 = w[2 * C1];
        float w3 = w[3 * C1];
        #pragma unroll
        for (int i = 0; i < NPW; ++i) {
            float x0 = bcast_lane(xv[i].x, k4);
            float x1 = bcast_lane(xv[i].y, k4);
            float x2 = bcast_lane(xv[i].z, k4);
            float x3 = bcast_lane(xv[i].w, k4);
            acc[i] = fmaf(x0, w0, acc[i]);
            acc[i] = fmaf(x1, w1, acc[i]);
            acc[i] = fmaf(x2, w2, acc[i]);
            acc[i] = fmaf(x3, w3, acc[i]);
        }
    }

    #pragma unroll
    for (int i = 0; i < NPW; ++i) {
        int n = n0 + i;
        if (n >= N) continue;
        h1[(size_t)n * C1 + lane] = fromF<T>(acc[i]);
        float vs = acc[i] * as_l;
        float vd = acc[i] * ad_l;
        #pragma unroll
        for (int off = 1; off < 8; off <<= 1) {
            vs += __shfl_xor(vs, off);
            vd += __shfl_xor(vd, off);
        }
        if ((lane & 7) == 0) {
            int h = lane >> 3;
            asrc1[n * H1 + h] = vs;
            adst1[n * H1 + h] = vd;
        }
    }
}

// ---------------- wsrc/wdst = W2 @ a_src2 / W2 @ a_dst2  (64 each) ----------------
__global__ __launch_bounds__(128) void k_wvec(const float* __restrict__ W2,
    const float* __restrict__ a_src2, const float* __restrict__ a_dst2,
    float* __restrict__ wsrc, float* __restrict__ wdst)
{
    int t = threadIdx.x;
    int k = t & 63;
    const float* a = (t < 64) ? a_src2 : a_dst2;
    float s = 0.f;
    for (int c = 0; c < D2; ++c) s = fmaf(W2[k * D2 + c], a[c], s);
    if (t < 64) wsrc[k] = s; else wdst[k] = s;
}

// ---------------- CSR build ----------------
__global__ void k_count(const int* __restrict__ ei, int E, int N,
                        int* __restrict__ deg)
{
    int tot = E + N;
    for (int e = blockIdx.x * blockDim.x + threadIdx.x; e < tot;
         e += gridDim.x * blockDim.x) {
        int dst = (e < E) ? ei[(size_t)E + e] : (e - E);
        atomicAdd(&deg[dst], 1);
    }
}

// scan phase A: per-chunk local exclusive scan (CH=1024 nodes per block, padded)
__global__ __launch_bounds__(256) void k_scanA(const int* __restrict__ deg,
    int* __restrict__ ptr, int* __restrict__ chunkSum)
{
    __shared__ int wtot[4];
    int b = blockIdx.x, t = threadIdx.x;
    int lane = t & 63, wave = t >> 6;
    int4 v = reinterpret_cast<const int4*>(deg + (size_t)b * CH)[t];
    int s = v.x + v.y + v.z + v.w;
    int incl = s;
    #pragma unroll
    for (int off = 1; off < 64; off <<= 1) {
        int tt = __shfl_up(incl, off);
        if (lane >= off) incl += tt;
    }
    if (lane == 63) wtot[wave] = incl;
    __syncthreads();
    int woff = 0;
    #pragma unroll
    for (int w = 0; w < 4; ++w) if (w < wave) woff += wtot[w];
    int excl = woff + incl - s;
    int i0 = b * CH + t * 4;
    ptr[i0 + 0] = excl;
    ptr[i0 + 1] = excl + v.x;
    ptr[i0 + 2] = excl + v.x + v.y;
    ptr[i0 + 3] = excl + v.x + v.y + v.z;
    if (t == 255) chunkSum[b] = woff + incl;
}

// scan phase B: serial scan over chunk sums (NB ~ 98, trivial)
__global__ void k_scanB(const int* __restrict__ chunkSum, int* __restrict__ chunkOff,
                        int NB, int* __restrict__ ptrN)
{
    if (threadIdx.x == 0) {
        int c = 0;
        for (int b = 0; b < NB; ++b) { chunkOff[b] = c; c += chunkSum[b]; }
        *ptrN = c;
    }
}

// scan phase C: add chunk offsets, init cursor
__global__ __launch_bounds__(256) void k_scanC(int* __restrict__ ptr,
    int* __restrict__ cursor, const int* __restrict__ chunkOff, int N)
{
    int b = blockIdx.x;
    int off = chunkOff[b];
    int i0 = b * CH + threadIdx.x * 4;
    #pragma unroll
    for (int k = 0; k < 4; ++k) {
        int i = i0 + k;
        if (i < N) { int v = ptr[i] + off; ptr[i] = v; cursor[i] = v; }
    }
}

__global__ void k_scatter(const int* __restrict__ ei, int E, int N,
                          int* __restrict__ cursor, int* __restrict__ edge_src)
{
    int tot = E + N;
    for (int e = blockIdx.x * blockDim.x + threadIdx.x; e < tot;
         e += gridDim.x * blockDim.x) {
        int src, dst;
        if (e < E) { src = ei[e]; dst = ei[(size_t)E + e]; }
        else       { src = e - E; dst = e - E; }
        int pos = atomicAdd(&cursor[dst], 1);
        edge_src[pos] = src;
    }
}

// -------- Layer-1 aggregation: online softmax, fused bias+ELU + alpha2 prep --------
// v3: 4 independent online-softmax chains per wave -> 4 gathers in flight
// (latency-bound loop; chain merge at end is exact).
template<typename T>
__global__ __launch_bounds__(256) void k_agg1(const int* __restrict__ ptr,
    const int* __restrict__ edge_src, const T* __restrict__ h1,
    const float* __restrict__ asrc1, const float* __restrict__ adst1,
    const float* __restrict__ b1, const float* __restrict__ wsrc,
    const float* __restrict__ wdst, T* __restrict__ hmid,
    float* __restrict__ asrc2, float* __restrict__ adst2, int N)
{
    int wave = threadIdx.x >> 6, lane = threadIdx.x & 63;
    int n = blockIdx.x * 4 + wave;
    if (n >= N) return;
    int h = lane >> 3;
    int start = ptr[n], end = ptr[n + 1];
    float adst = adst1[n * H1 + h];

    float m0 = -1e30f, m1 = -1e30f, m2 = -1e30f, m3 = -1e30f;
    float s0 = 0.f, s1 = 0.f, s2 = 0.f, s3 = 0.f;
    float a0 = 0.f, a1 = 0.f, a2 = 0.f, a3 = 0.f;

    int e = start;
    for (; e + 4 <= end; e += 4) {
        int i0 = edge_src[e + 0];
        int i1 = edge_src[e + 1];
        int i2 = edge_src[e + 2];
        int i3 = edge_src[e + 3];
        float ev0 = asrc1[i0 * H1 + h] + adst;
        float ev1 = asrc1[i1 * H1 + h] + adst;
        float ev2 = asrc1[i2 * H1 + h] + adst;
        float ev3 = asrc1[i3 * H1 + h] + adst;
        float h0 = toF(h1[(size_t)i0 * C1 + lane]);
        float h1v = toF(h1[(size_t)i1 * C1 + lane]);
        float h2 = toF(h1[(size_t)i2 * C1 + lane]);
        float h3 = toF(h1[(size_t)i3 * C1 + lane]);
        ev0 = ev0 > 0.f ? ev0 : NEG * ev0;
        ev1 = ev1 > 0.f ? ev1 : NEG * ev1;
        ev2 = ev2 > 0.f ? ev2 : NEG * ev2;
        ev3 = ev3 > 0.f ? ev3 : NEG * ev3;
        chain_upd(ev0, h0,  m0, s0, a0);
        chain_upd(ev1, h1v, m1, s1, a1);
        chain_upd(ev2, h2,  m2, s2, a2);
        chain_upd(ev3, h3,  m3, s3, a3);
    }
    for (; e < end; ++e) {
        int s = edge_src[e];
        float ev = asrc1[s * H1 + h] + adst;
        ev = ev > 0.f ? ev : NEG * ev;
        float hv = toF(h1[(size_t)s * C1 + lane]);
        chain_upd(ev, hv, m0, s0, a0);
    }
    // merge 4 chains
    float M = fmaxf(fmaxf(m0, m1), fmaxf(m2, m3));
    float e0 = __expf(m0 - M), e1 = __expf(m1 - M);
    float e2 = __expf(m2 - M), e3 = __expf(m3 - M);
    float sum = fmaf(s0, e0, fmaf(s1, e1, fmaf(s2, e2, s3 * e3)));
    float acc = fmaf(a0, e0, fmaf(a1, e1, fmaf(a2, e2, a3 * e3)));

    float o = acc / (sum + EPSS) + b1[lane];
    o = o > 0.f ? o : (expf(o) - 1.f);   // ELU
    hmid[(size_t)n * C1 + lane] = fromF<T>(o);
    float vs = o * wsrc[lane];
    float vd = o * wdst[lane];
    #pragma unroll
    for (int off = 1; off < 64; off <<= 1) {
        vs += __shfl_xor(vs, off);
        vd += __shfl_xor(vd, off);
    }
    if (lane == 0) { asrc2[n] = vs; adst2[n] = vd; }
}

// ------ Layer-2: online-softmax aggregation in hmid-space + fused W2 GEMM + bias ------
template<typename T>
__global__ __launch_bounds__(256) void k_agg2out(const int* __restrict__ ptr,
    const int* __restrict__ edge_src, const T* __restrict__ hmid,
    const float* __restrict__ asrc2, const float* __restrict__ adst2,
    const float* __restrict__ W2, const float* __restrict__ b2,
    float* __restrict__ out, int N)
{
    __shared__ float Ws[C1 * D2];                  // 32 KB
    for (int i = threadIdx.x; i < C1 * D2; i += 256) Ws[i] = W2[i];
    __syncthreads();
    int wave = threadIdx.x >> 6, lane = threadIdx.x & 63;
    int n = blockIdx.x * 4 + wave;
    if (n >= N) return;
    int start = ptr[n], end = ptr[n + 1];
    float adst = adst2[n];

    float m0 = -1e30f, m1 = -1e30f, m2 = -1e30f, m3 = -1e30f;
    float s0 = 0.f, s1 = 0.f, s2 = 0.f, s3 = 0.f;
    float a0 = 0.f, a1 = 0.f, a2 = 0.f, a3 = 0.f;

    int e = start;
    for (; e + 4 <= end; e += 4) {
        int i0 = edge_src[e + 0];
        int i1 = edge_src[e + 1];
        int i2 = edge_src[e + 2];
        int i3 = edge_src[e + 3];
        float ev0 = asrc2[i0] + adst;
        float ev1 = asrc2[i1] + adst;
        float ev2 = asrc2[i2] + adst;
        float ev3 = asrc2[i3] + adst;
        float h0 = toF(hmid[(size_t)i0 * C1 + lane]);
        float h1v = toF(hmid[(size_t)i1 * C1 + lane]);
        float h2 = toF(hmid[(size_t)i2 * C1 + lane]);
        float h3 = toF(hmid[(size_t)i3 * C1 + lane]);
        ev0 = ev0 > 0.f ? ev0 : NEG * ev0;
        ev1 = ev1 > 0.f ? ev1 : NEG * ev1;
        ev2 = ev2 > 0.f ? ev2 : NEG * ev2;
        ev3 = ev3 > 0.f ? ev3 : NEG * ev3;
        chain_upd(ev0, h0,  m0, s0, a0);
        chain_upd(ev1, h1v, m1, s1, a1);
        chain_upd(ev2, h2,  m2, s2, a2);
        chain_upd(ev3, h3,  m3, s3, a3);
    }
    for (; e < end; ++e) {
        int s = edge_src[e];
        float ev = asrc2[s] + adst;
        ev = ev > 0.f ? ev : NEG * ev;
        float hv = toF(hmid[(size_t)s * C1 + lane]);
        chain_upd(ev, hv, m0, s0, a0);
    }
    float M = fmaxf(fmaxf(m0, m1), fmaxf(m2, m3));
    float e0 = __expf(m0 - M), e1 = __expf(m1 - M);
    float e2 = __expf(m2 - M), e3 = __expf(m3 - M);
    float sum = fmaf(s0, e0, fmaf(s1, e1, fmaf(s2, e2, s3 * e3)));
    float acc = fmaf(a0, e0, fmaf(a1, e1, fmaf(a2, e2, a3 * e3)));

    float aggv = acc / (sum + EPSS);
    float acc0 = 0.f, acc1 = 0.f;
    #pragma unroll
    for (int k = 0; k < 64; ++k) {
        float xk = bcast_lane(aggv, k);
        acc0 = fmaf(xk, Ws[k * D2 + lane], acc0);
        acc1 = fmaf(xk, Ws[k * D2 + 64 + lane], acc1);
    }
    out[(size_t)n * D2 + lane]      = acc0 + b2[lane];
    out[(size_t)n * D2 + 64 + lane] = acc1 + b2[64 + lane];
}

extern "C" void kernel_launch(void* const* d_in, const int* in_sizes, int n_in,
                              void* d_out, int out_size, void* d_ws, size_t ws_size,
                              hipStream_t stream)
{
    const float* x      = (const float*)d_in[0];
    const int*   ei     = (const int*)d_in[1];
    const float* W1     = (const float*)d_in[2];
    const float* a_src1 = (const float*)d_in[3];
    const float* a_dst1 = (const float*)d_in[4];
    const float* b1     = (const float*)d_in[5];
    const float* W2     = (const float*)d_in[6];
    const float* a_src2 = (const float*)d_in[7];
    const float* a_dst2 = (const float*)d_in[8];
    const float* b2     = (const float*)d_in[9];
    float* out = (float*)d_out;

    const int N = in_sizes[0] / FIN;
    const int E = in_sizes[1] / 2;
    const int Etot = E + N;
    const int NB = (N + CH - 1) / CH;     // scan chunks
    const size_t NP = (size_t)NB * CH;    // padded node count

    // workspace requirement: common part + 2 * N*C1 * elemsize
    const size_t common =
        ((size_t)N * H1 * 4 + 255 & ~(size_t)255) * 2 +   // asrc1, adst1
        (((size_t)N * 4 + 255) & ~(size_t)255) * 2 +       // asrc2, adst2
        512 +                                              // wsrc, wdst
        (((size_t)NP * 4 + 255) & ~(size_t)255) * 2 +      // deg, cursor
        (((size_t)(NP + 1) * 4 + 255) & ~(size_t)255) +    // ptr
        (((size_t)NB * 4 + 255) & ~(size_t)255) * 2 +      // chunkSum, chunkOff
        (((size_t)Etot * 4 + 255) & ~(size_t)255) +        // edge_src
        4096;                                              // slack
    const bool f32path = ws_size >= common + 2 * ((size_t)N * C1 * 4 + 256);

    char* ws = (char*)d_ws;
    size_t off = 0;
    auto alloc = [&](size_t bytes) -> void* {
        void* p = ws + off;
        off = (off + bytes + 255) & ~(size_t)255;
        return p;
    };
    const size_t es = f32path ? 4 : 2;
    void*  h1v    = alloc((size_t)N * C1 * es);
    void*  hmidv  = alloc((size_t)N * C1 * es);
    float* asrc1  = (float*)alloc((size_t)N * H1 * 4);
    float* adst1  = (float*)alloc((size_t)N * H1 * 4);
    float* asrc2  = (float*)alloc((size_t)N * 4);
    float* adst2  = (float*)alloc((size_t)N * 4);
    float* wsrc   = (float*)alloc(64 * 4);
    float* wdst   = (float*)alloc(64 * 4);
    int*   deg    = (int*)alloc(NP * 4);
    int*   ptr    = (int*)alloc((NP + 1) * 4);
    int*   cursor = (int*)alloc(NP * 4);
    int*   chunkSum = (int*)alloc((size_t)NB * 4);
    int*   chunkOff = (int*)alloc((size_t)NB * 4);
    int*   edge_src = (int*)alloc((size_t)Etot * 4);

    const int nodeBlocks = (N + 3) / 4;
    const int g1Blocks = (N + NPB - 1) / NPB;

    // CSR build (dst-indexed)
    hipMemsetAsync(deg, 0, NP * 4, stream);
    k_count<<<2048, 256, 0, stream>>>(ei, E, N, deg);
    k_scanA<<<NB, 256, 0, stream>>>(deg, ptr, chunkSum);
    k_scanB<<<1, 64, 0, stream>>>(chunkSum, chunkOff, NB, ptr + N);
    k_scanC<<<NB, 256, 0, stream>>>(ptr, cursor, chunkOff, N);
    k_scatter<<<2048, 256, 0, stream>>>(ei, E, N, cursor, edge_src);

    k_wvec<<<1, 128, 0, stream>>>(W2, a_src2, a_dst2, wsrc, wdst);

    if (f32path) {
        float* h1 = (float*)h1v; float* hmid = (float*)hmidv;
        k_gemm1<float><<<g1Blocks, 256, 0, stream>>>(x, W1, a_src1, a_dst1, h1, asrc1, adst1, N);
        k_agg1<float><<<nodeBlocks, 256, 0, stream>>>(ptr, edge_src, h1, asrc1, adst1, b1,
                                                      wsrc, wdst, hmid, asrc2, adst2, N);
        k_agg2out<float><<<nodeBlocks, 256, 0, stream>>>(ptr, edge_src, hmid, asrc2, adst2,
                                                         W2, b2, out, N);
    } else {
        __hip_bfloat16* h1 = (__hip_bfloat16*)h1v; __hip_bfloat16* hmid = (__hip_bfloat16*)hmidv;
        k_gemm1<__hip_bfloat16><<<g1Blocks, 256, 0, stream>>>(x, W1, a_src1, a_dst1, h1, asrc1, adst1, N);
        k_agg1<__hip_bfloat16><<<nodeBlocks, 256, 0, stream>>>(ptr, edge_src, h1, asrc1, adst1, b1,
                                                               wsrc, wdst, hmid, asrc2, adst2, N);
        k_agg2out<__hip_bfloat16><<<nodeBlocks, 256, 0, stream>>>(ptr, edge_src, hmid, asrc2, adst2,
                                                                  W2, b2, out, N);
    }
}